// Round 8
// baseline (383.200 us; speedup 1.0000x reference)
//
#include <hip/hip_runtime.h>

typedef int int32x4 __attribute__((ext_vector_type(4)));

// ---------------------------------------------------------------------------
// maxabs reduction (for weight_scale = max|W| / 7)
// ---------------------------------------------------------------------------
__global__ void maxabs_kernel(const float* __restrict__ x, int n4,
                              unsigned* __restrict__ out) {
    float m = 0.f;
    int i = blockIdx.x * blockDim.x + threadIdx.x;
    int stride = gridDim.x * blockDim.x;
    const float4* x4 = (const float4*)x;
    for (int j = i; j < n4; j += stride) {
        float4 v = x4[j];
        m = fmaxf(m, fmaxf(fmaxf(fabsf(v.x), fabsf(v.y)),
                           fmaxf(fabsf(v.z), fabsf(v.w))));
    }
#pragma unroll
    for (int off = 32; off; off >>= 1)
        m = fmaxf(m, __shfl_down(m, off, 64));
    __shared__ float wm[4];
    int ln = threadIdx.x & 63, wv = threadIdx.x >> 6;
    if (ln == 0) wm[wv] = m;
    __syncthreads();
    if (threadIdx.x == 0) {
        float bm = fmaxf(fmaxf(wm[0], wm[1]), fmaxf(wm[2], wm[3]));
        atomicMax(out, __float_as_uint(bm));  // nonneg floats: bit order ok
    }
}

// ---------------------------------------------------------------------------
// fake-quant to int8 codes in BLOCKED-PRESWIZZLED layout:
//   out[blk][row][c][b] (16384 B blocks, blk = rowblk*(K/128)+kblk)
//   stored[row][c] = orig[row][c ^ (row&7)]  (the exact LDS image the GEMM
//   expects, so GEMM staging is a contiguous 16 KB copy, rule #21).
// One thread per 4 output bytes (one float4 read, 16-B aligned).
// ---------------------------------------------------------------------------
__global__ void quant_blocked_kernel(const float* __restrict__ src, int n4,
                                     int K, int kshift,
                                     const float* __restrict__ sptr, float sdiv,
                                     float lo, float hi, int* __restrict__ out) {
    float s = sptr[0] / sdiv;
    int i0 = blockIdx.x * blockDim.x + threadIdx.x;
    int stride = gridDim.x * blockDim.x;
    for (int o = i0; o < n4; o += stride) {
        int blk = o >> 12;            // 4096 int-groups per 16 KB block
        int i = o & 4095;
        int row = i >> 5;             // 32 groups per 128-B row
        int c = (i >> 2) & 7;         // stored 16-B chunk
        int b4 = i & 3;               // float4 within chunk
        int rowblk = blk >> kshift;
        int kblk = blk & ((1 << kshift) - 1);
        int co = c ^ (row & 7);       // original chunk
        long srcoff = (long)(rowblk * 128 + row) * K + (kblk << 7) + (co << 4) + (b4 << 2);
        float4 v = *(const float4*)(src + srcoff);
        int a = (int)fminf(fmaxf(rintf(v.x / s), lo), hi);
        int b = (int)fminf(fmaxf(rintf(v.y / s), lo), hi);
        int cc = (int)fminf(fmaxf(rintf(v.z / s), lo), hi);
        int d = (int)fminf(fmaxf(rintf(v.w / s), lo), hi);
        out[o] = (a & 255) | ((b & 255) << 8) | ((cc & 255) << 16) | ((d & 255) << 24);
    }
}

// ---------------------------------------------------------------------------
// int8 GEMM, C[m,n] = sum_k A[m,k]*B[n,k], operands in blocked-preswizzled
// layout ([rowblk][kblk][16384 B]). Round-1 verified compute structure:
// 128x128 tile, BK=128 B, 4 waves (2x2), single-buffer 32 KiB LDS,
// 16x16x64 MFMA, 0-conflict swizzled ds_read_b128, 2 barriers/K-tile.
// CHANGED vs round 7: __launch_bounds__(256, 5) -> request 5 blocks/CU
// (5 x 32 KiB = 160 KiB LDS exactly; 56 VGPR allows it). Mechanism: on
// this structure stall-filling is multi-block TLP (m114) — occupancy 3.3
// blocks gave 42% MfmaUtil, 1 block gave 28%; push to 5.
// ---------------------------------------------------------------------------
template <bool FIRST>
__global__ __launch_bounds__(256, 5)
void gemm_i8_kernel(const char* __restrict__ A, const char* __restrict__ B,
                    int N, int nkt,
                    const float* __restrict__ sa_ptr,
                    const float* __restrict__ wmax_ptr,
                    const float* __restrict__ bias,
                    const float* __restrict__ s2_ptr,
                    char* __restrict__ out8, float* __restrict__ outf) {
    __shared__ __align__(16) char lA[128 * 128];
    __shared__ __align__(16) char lB[128 * 128];

    const int tid = threadIdx.x;
    const int wv = tid >> 6, ln = tid & 63;
    const int lnlo = ln & 15, lnhi = ln >> 4;
    const int wr = wv >> 1, wc = wv & 1;

    int32x4 acc[4][4] = {};

    // blocked operand bases: block index = rowblk*nkt + kt
    const char* pa = A + ((size_t)blockIdx.y * nkt << 14);
    const char* pb = B + ((size_t)blockIdx.x * nkt << 14);

    for (int kt = 0; kt < nkt; ++kt) {
        // ---- stage: contiguous 16 KB copy per operand ----
#pragma unroll
        for (int r = 0; r < 4; ++r) {
            int off = (r * 256 + tid) * 16;
            int lbase = (r * 256 + wv * 64) * 16;  // wave-uniform base (+ln*16 by HW)
            __builtin_amdgcn_global_load_lds(
                (const __attribute__((address_space(1))) void*)(pa + off),
                (__attribute__((address_space(3))) void*)(lA + lbase), 16, 0, 0);
            __builtin_amdgcn_global_load_lds(
                (const __attribute__((address_space(1))) void*)(pb + off),
                (__attribute__((address_space(3))) void*)(lB + lbase), 16, 0, 0);
        }
        pa += 16384;
        pb += 16384;
        __syncthreads();

        // ---- LDS -> fragments (identical to round 1, measured 0 conflicts) ----
        int32x4 af[4][2], bf[4][2];
#pragma unroll
        for (int mf = 0; mf < 4; ++mf)
#pragma unroll
            for (int kk = 0; kk < 2; ++kk) {
                int row = wr * 64 + mf * 16 + lnlo;
                int ch = kk * 4 + lnhi;
                af[mf][kk] = *(const int32x4*)(lA + row * 128 + ((ch ^ (row & 7)) * 16));
            }
#pragma unroll
        for (int nf = 0; nf < 4; ++nf)
#pragma unroll
            for (int kk = 0; kk < 2; ++kk) {
                int col = wc * 64 + nf * 16 + lnlo;
                int ch = kk * 4 + lnhi;
                bf[nf][kk] = *(const int32x4*)(lB + col * 128 + ((ch ^ (col & 7)) * 16));
            }

        // ---- MFMA ----
#pragma unroll
        for (int kk = 0; kk < 2; ++kk)
#pragma unroll
            for (int mf = 0; mf < 4; ++mf)
#pragma unroll
                for (int nf = 0; nf < 4; ++nf)
                    acc[mf][nf] = __builtin_amdgcn_mfma_i32_16x16x64_i8(
                        af[mf][kk], bf[nf][kk], acc[mf][nf], 0, 0, 0);
        __syncthreads();
    }

    // ---- epilogue ----
    float sa = sa_ptr[0];
    float sw = wmax_ptr[0] / 7.0f;  // weight_scale
    float sab = sa * sw;
    float s2v = FIRST ? s2_ptr[0] : 0.f;

    // hq destination block (GEMM1): [mblk][fblk] = [blockIdx.y][blockIdx.x]
    char* hblk = FIRST ? out8 + (((size_t)blockIdx.y * gridDim.x + blockIdx.x) << 14)
                       : nullptr;

#pragma unroll
    for (int nf = 0; nf < 4; ++nf) {
        int lc = wc * 64 + nf * 16 + lnlo;               // local col 0..127
        long col = (long)blockIdx.x * 128 + lc;          // global col
        float bq = rintf(bias[col] / sab) * sab;         // Int32Bias fake-quant
#pragma unroll
        for (int mf = 0; mf < 4; ++mf) {
            int lr0 = wr * 64 + mf * 16 + (lnhi << 2);   // local row base
#pragma unroll
            for (int i = 0; i < 4; ++i) {
                int lr = lr0 + i;
                float h = sab * (float)acc[mf][nf][i] + bq;
                if constexpr (FIRST) {
                    h = fmaxf(h, 0.f);
                    float qv = fminf(fmaxf(rintf(h / s2v), 0.f), 15.f);
                    // blocked-preswizzled store: stored[lr][c]=orig[lr][c^(lr&7)]
                    hblk[lr * 128 + (((lc >> 4) ^ (lr & 7)) << 4) + (lc & 15)] =
                        (char)(int)qv;
                } else {
                    outf[((long)blockIdx.y * 128 + lr) * N + col] = h;
                }
            }
        }
    }
}

// ---------------------------------------------------------------------------
// launch
// ---------------------------------------------------------------------------
extern "C" void kernel_launch(void* const* d_in, const int* in_sizes, int n_in,
                              void* d_out, int out_size, void* d_ws, size_t ws_size,
                              hipStream_t stream) {
    const float* x  = (const float*)d_in[0];   // [4,2048,2048] -> [8192,2048]
    const float* W1 = (const float*)d_in[1];   // [8192,2048]
    const float* b1 = (const float*)d_in[2];   // [8192]
    const float* W2 = (const float*)d_in[3];   // [2048,8192]
    const float* b2 = (const float*)d_in[4];   // [2048]
    const float* s1 = (const float*)d_in[5];
    const float* s2 = (const float*)d_in[6];

    const int M = 8192, D = 2048, F = 8192;

    char* ws = (char*)d_ws;
    unsigned* mx1 = (unsigned*)ws;        // maxabs(W1) as float bits
    unsigned* mx2 = (unsigned*)(ws + 4);  // maxabs(W2)
    char* xq  = ws + 256;                  // [M/128][D/128][16384]
    char* w1q = xq + (size_t)M * D;        // [F/128][D/128][16384]
    char* w2q = w1q + (size_t)F * D;       // [D/128][F/128][16384]
    char* hq  = w2q + (size_t)D * F;       // [M/128][F/128][16384]

    hipMemsetAsync(d_ws, 0, 8, stream);   // zero the maxabs slots

    maxabs_kernel<<<2048, 256, 0, stream>>>(W1, (F * D) >> 2, mx1);
    maxabs_kernel<<<2048, 256, 0, stream>>>(W2, (D * F) >> 2, mx2);

    // blocked-preswizzled quant: kshift = log2(K/128)
    quant_blocked_kernel<<<2048, 256, 0, stream>>>(
        x,  (M * D) >> 2, D, 4, s1, 1.f, -8.f, 7.f, (int*)xq);
    quant_blocked_kernel<<<2048, 256, 0, stream>>>(
        W1, (F * D) >> 2, D, 4, (const float*)mx1, 7.f, -8.f, 7.f, (int*)w1q);
    quant_blocked_kernel<<<2048, 256, 0, stream>>>(
        W2, (D * F) >> 2, F, 6, (const float*)mx2, 7.f, -8.f, 7.f, (int*)w2q);

    // h_q = clip(round(relu(x_q W1_q^T + b1_q)/s2),0,15) -> blocked int8
    gemm_i8_kernel<true><<<dim3(F / 128, M / 128), 256, 0, stream>>>(
        xq, w1q, F, D / 128, s1, (const float*)mx1, b1, s2, hq, nullptr);

    // out = s2*sw2 * (h_int W2_int^T) + b2_q
    gemm_i8_kernel<false><<<dim3(D / 128, M / 128), 256, 0, stream>>>(
        hq, w2q, D, F / 128, s2, (const float*)mx2, b2, nullptr, nullptr,
        (float*)d_out);
}

// Round 9
// 375.434 us; speedup vs baseline: 1.0207x; 1.0207x over previous
//
#include <hip/hip_runtime.h>

typedef int int32x4 __attribute__((ext_vector_type(4)));

// ---------------------------------------------------------------------------
// maxabs reduction (for weight_scale = max|W| / 7)
// ---------------------------------------------------------------------------
__global__ void maxabs_kernel(const float* __restrict__ x, int n4,
                              unsigned* __restrict__ out) {
    float m = 0.f;
    int i = blockIdx.x * blockDim.x + threadIdx.x;
    int stride = gridDim.x * blockDim.x;
    const float4* x4 = (const float4*)x;
    for (int j = i; j < n4; j += stride) {
        float4 v = x4[j];
        m = fmaxf(m, fmaxf(fmaxf(fabsf(v.x), fabsf(v.y)),
                           fmaxf(fabsf(v.z), fabsf(v.w))));
    }
#pragma unroll
    for (int off = 32; off; off >>= 1)
        m = fmaxf(m, __shfl_down(m, off, 64));
    __shared__ float wm[4];
    int ln = threadIdx.x & 63, wv = threadIdx.x >> 6;
    if (ln == 0) wm[wv] = m;
    __syncthreads();
    if (threadIdx.x == 0) {
        float bm = fmaxf(fmaxf(wm[0], wm[1]), fmaxf(wm[2], wm[3]));
        atomicMax(out, __float_as_uint(bm));  // nonneg floats: bit order ok
    }
}

// ---------------------------------------------------------------------------
// fake-quant to int8 in BK=64 BLOCKED-PRESWIZZLED layout:
// 8192-B blocks, blk = rowblk*(K/64)+kblk; in-block "virtual 128-B rows":
//   v = row>>1, vc = (row&1)*4 + chunk(16B), stored chunk = vc ^ (v&7)
// This is the exact LDS image the GEMM expects (contiguous-copy staging,
// rule #21), and each frag ds_read_b128 covers 8 v-rows x 8 distinct
// chunk-slots = exact 32-bank cover -> 0 extra conflicts by construction.
// ---------------------------------------------------------------------------
__global__ void quant_blocked_kernel(const float* __restrict__ src, int n4,
                                     int K, int kshift,
                                     const float* __restrict__ sptr, float sdiv,
                                     float lo, float hi, int* __restrict__ out) {
    float s = sptr[0] / sdiv;
    int i0 = blockIdx.x * blockDim.x + threadIdx.x;
    int stride = gridDim.x * blockDim.x;
    for (int o = i0; o < n4; o += stride) {
        int blk = o >> 11;            // 2048 int-groups per 8 KB block
        int i = o & 2047;
        int v = i >> 5;               // virtual row (2 real rows)
        int sc = (i >> 2) & 7;        // stored chunk in virtual row
        int w = i & 3;                // float4 within chunk
        int vc = sc ^ (v & 7);        // unswizzled virtual chunk
        int row = (v << 1) | (vc >> 2);
        int chunk = vc & 3;
        int rowblk = blk >> kshift;
        int kblk = blk & ((1 << kshift) - 1);
        long srcoff = (long)(rowblk * 128 + row) * K + (kblk << 6) + (chunk << 4) + (w << 2);
        float4 f = *(const float4*)(src + srcoff);
        int a = (int)fminf(fmaxf(rintf(f.x / s), lo), hi);
        int b = (int)fminf(fmaxf(rintf(f.y / s), lo), hi);
        int c = (int)fminf(fmaxf(rintf(f.z / s), lo), hi);
        int d = (int)fminf(fmaxf(rintf(f.w / s), lo), hi);
        out[o] = (a & 255) | ((b & 255) << 8) | ((c & 255) << 16) | ((d & 255) << 24);
    }
}

// ---------------------------------------------------------------------------
// int8 GEMM, C[m,n] = sum_k A[m,k]*B[n,k], operands in BK=64 blocked layout
// ([rowblk][kblk][8192 B]). r7 skeleton with HALVED LDS (16 KiB/block):
// 128x128 tile, BK=64 B, 4 waves (2x2), single-buffer 2x8 KiB LDS,
// 16 MFMA (16x16x64) per K-tile, contiguous 16-B-slot staging, 2 barriers
// per K-tile. Mechanism: 16 KiB LDS + ~120 unified regs -> 4 blocks/CU
// (was 3.3 at 32 KiB; cross-round ladder says blocks/CU drives MfmaUtil).
// ---------------------------------------------------------------------------
template <bool FIRST>
__global__ __launch_bounds__(256, 4)
void gemm_i8_kernel(const char* __restrict__ A, const char* __restrict__ B,
                    int N, int nkt,
                    const float* __restrict__ sa_ptr,
                    const float* __restrict__ wmax_ptr,
                    const float* __restrict__ bias,
                    const float* __restrict__ s2_ptr,
                    char* __restrict__ out8, float* __restrict__ outf) {
    __shared__ __align__(16) char lA[128 * 64];   // 8 KiB (64 v-rows x 128 B)
    __shared__ __align__(16) char lB[128 * 64];   // 8 KiB

    const int tid = threadIdx.x;
    const int wv = tid >> 6, ln = tid & 63;
    const int lnlo = ln & 15, lnhi = ln >> 4;
    const int wr = wv >> 1, wc = wv & 1;

    int32x4 acc[4][4] = {};

    // blocked operand bases: block index = rowblk*nkt + kt
    const char* pa = A + ((size_t)blockIdx.y * nkt << 13);
    const char* pb = B + ((size_t)blockIdx.x * nkt << 13);

    for (int kt = 0; kt < nkt; ++kt) {
        // ---- stage: contiguous 8 KB copy per operand (2 loads/thread) ----
#pragma unroll
        for (int r = 0; r < 2; ++r) {
            int off = (r * 256 + tid) * 16;
            int lbase = (r * 256 + wv * 64) * 16;  // wave-uniform base (+ln*16 by HW)
            __builtin_amdgcn_global_load_lds(
                (const __attribute__((address_space(1))) void*)(pa + off),
                (__attribute__((address_space(3))) void*)(lA + lbase), 16, 0, 0);
            __builtin_amdgcn_global_load_lds(
                (const __attribute__((address_space(1))) void*)(pb + off),
                (__attribute__((address_space(3))) void*)(lB + lbase), 16, 0, 0);
        }
        pa += 8192;
        pb += 8192;
        __syncthreads();

        // ---- LDS -> fragments (virtual-row swizzle, exact bank cover) ----
        int32x4 af[4], bf[4];
#pragma unroll
        for (int mf = 0; mf < 4; ++mf) {
            int row = wr * 64 + mf * 16 + lnlo;
            int v = row >> 1;
            int vc = ((row & 1) << 2) | lnhi;
            af[mf] = *(const int32x4*)(lA + v * 128 + ((vc ^ (v & 7)) << 4));
        }
#pragma unroll
        for (int nf = 0; nf < 4; ++nf) {
            int col = wc * 64 + nf * 16 + lnlo;
            int v = col >> 1;
            int vc = ((col & 1) << 2) | lnhi;
            bf[nf] = *(const int32x4*)(lB + v * 128 + ((vc ^ (v & 7)) << 4));
        }

        // ---- MFMA: 16 x 16x16x64 i8 ----
#pragma unroll
        for (int mf = 0; mf < 4; ++mf)
#pragma unroll
            for (int nf = 0; nf < 4; ++nf)
                acc[mf][nf] = __builtin_amdgcn_mfma_i32_16x16x64_i8(
                    af[mf], bf[nf], acc[mf][nf], 0, 0, 0);
        __syncthreads();
    }

    // ---- epilogue ----
    float sa = sa_ptr[0];
    float sw = wmax_ptr[0] / 7.0f;  // weight_scale
    float sab = sa * sw;
    float s2v = FIRST ? s2_ptr[0] : 0.f;

#pragma unroll
    for (int nf = 0; nf < 4; ++nf) {
        int lc = wc * 64 + nf * 16 + lnlo;               // local col 0..127
        long col = (long)blockIdx.x * 128 + lc;          // global col
        float bq = rintf(bias[col] / sab) * sab;         // Int32Bias fake-quant
#pragma unroll
        for (int mf = 0; mf < 4; ++mf) {
            int lr0 = wr * 64 + mf * 16 + (lnhi << 2);   // local row base
#pragma unroll
            for (int i = 0; i < 4; ++i) {
                int lr = lr0 + i;
                float h = sab * (float)acc[mf][nf][i] + bq;
                if constexpr (FIRST) {
                    h = fmaxf(h, 0.f);
                    float qv = fminf(fmaxf(rintf(h / s2v), 0.f), 15.f);
                    // hq in BK=64 blocked layout for GEMM2:
                    // kblk = bx*2 + (lc>>6); virtual-row swizzled in-block
                    int kblk = (blockIdx.x << 1) | (lc >> 6);
                    int l6 = lc & 63;
                    int v = lr >> 1;
                    int vc = ((lr & 1) << 2) | (l6 >> 4);
                    size_t blkoff =
                        ((size_t)blockIdx.y * (gridDim.x << 1) + kblk) << 13;
                    out8[blkoff + v * 128 + ((vc ^ (v & 7)) << 4) + (lc & 15)] =
                        (char)(int)qv;
                } else {
                    outf[((long)blockIdx.y * 128 + lr) * N + col] = h;
                }
            }
        }
    }
}

// ---------------------------------------------------------------------------
// launch
// ---------------------------------------------------------------------------
extern "C" void kernel_launch(void* const* d_in, const int* in_sizes, int n_in,
                              void* d_out, int out_size, void* d_ws, size_t ws_size,
                              hipStream_t stream) {
    const float* x  = (const float*)d_in[0];   // [4,2048,2048] -> [8192,2048]
    const float* W1 = (const float*)d_in[1];   // [8192,2048]
    const float* b1 = (const float*)d_in[2];   // [8192]
    const float* W2 = (const float*)d_in[3];   // [2048,8192]
    const float* b2 = (const float*)d_in[4];   // [2048]
    const float* s1 = (const float*)d_in[5];
    const float* s2 = (const float*)d_in[6];

    const int M = 8192, D = 2048, F = 8192;

    char* ws = (char*)d_ws;
    unsigned* mx1 = (unsigned*)ws;        // maxabs(W1) as float bits
    unsigned* mx2 = (unsigned*)(ws + 4);  // maxabs(W2)
    char* xq  = ws + 256;                  // [M/128][D/64][8192]
    char* w1q = xq + (size_t)M * D;        // [F/128][D/64][8192]
    char* w2q = w1q + (size_t)F * D;       // [D/128][F/64][8192]
    char* hq  = w2q + (size_t)D * F;       // [M/128][F/64][8192]

    hipMemsetAsync(d_ws, 0, 8, stream);   // zero the maxabs slots

    maxabs_kernel<<<2048, 256, 0, stream>>>(W1, (F * D) >> 2, mx1);
    maxabs_kernel<<<2048, 256, 0, stream>>>(W2, (D * F) >> 2, mx2);

    // blocked-preswizzled quant: kshift = log2(K/64)
    quant_blocked_kernel<<<2048, 256, 0, stream>>>(
        x,  (M * D) >> 2, D, 5, s1, 1.f, -8.f, 7.f, (int*)xq);
    quant_blocked_kernel<<<2048, 256, 0, stream>>>(
        W1, (F * D) >> 2, D, 5, (const float*)mx1, 7.f, -8.f, 7.f, (int*)w1q);
    quant_blocked_kernel<<<2048, 256, 0, stream>>>(
        W2, (D * F) >> 2, F, 7, (const float*)mx2, 7.f, -8.f, 7.f, (int*)w2q);

    // h_q = clip(round(relu(x_q W1_q^T + b1_q)/s2),0,15) -> blocked int8
    gemm_i8_kernel<true><<<dim3(F / 128, M / 128), 256, 0, stream>>>(
        xq, w1q, F, D / 64, s1, (const float*)mx1, b1, s2, hq, nullptr);

    // out = s2*sw2 * (h_int W2_int^T) + b2_q
    gemm_i8_kernel<false><<<dim3(D / 128, M / 128), 256, 0, stream>>>(
        hq, w2q, D, F / 64, s2, (const float*)mx2, b2, nullptr, nullptr,
        (float*)d_out);
}

// Round 10
// 372.853 us; speedup vs baseline: 1.0278x; 1.0069x over previous
//
#include <hip/hip_runtime.h>

typedef int int32x4 __attribute__((ext_vector_type(4)));

// ---------------------------------------------------------------------------
// maxabs reduction for W1 and W2 in one launch (blockIdx.y selects tensor)
// ---------------------------------------------------------------------------
__global__ void maxabs2_kernel(const float* __restrict__ w1,
                               const float* __restrict__ w2, int n4,
                               unsigned* __restrict__ out) {
    const float4* x4 = (const float4*)(blockIdx.y ? w2 : w1);
    float m = 0.f;
    int i = blockIdx.x * blockDim.x + threadIdx.x;
    int stride = gridDim.x * blockDim.x;
    for (int j = i; j < n4; j += stride) {
        float4 v = x4[j];
        m = fmaxf(m, fmaxf(fmaxf(fabsf(v.x), fabsf(v.y)),
                           fmaxf(fabsf(v.z), fabsf(v.w))));
    }
#pragma unroll
    for (int off = 32; off; off >>= 1)
        m = fmaxf(m, __shfl_down(m, off, 64));
    __shared__ float wm[4];
    int ln = threadIdx.x & 63, wv = threadIdx.x >> 6;
    if (ln == 0) wm[wv] = m;
    __syncthreads();
    if (threadIdx.x == 0) {
        float bm = fmaxf(fmaxf(wm[0], wm[1]), fmaxf(wm[2], wm[3]));
        atomicMax(out + blockIdx.y, __float_as_uint(bm));  // nonneg: bit order ok
    }
}

// ---------------------------------------------------------------------------
// fake-quant to int8 in BK=64 BLOCKED-PRESWIZZLED layout (verified r9):
// 8192-B blocks, blk = rowblk*(K/64)+kblk; in-block "virtual 128-B rows":
//   v = row>>1, vc = (row&1)*4 + chunk(16B), stored chunk = vc ^ (v&7)
// Exact LDS image the GEMM expects (contiguous-copy staging, rule #21);
// each frag ds_read_b128 covers 8 v-rows x 8 distinct chunk-slots = exact
// 32-bank cover -> 0 extra conflicts (measured r9).
// ---------------------------------------------------------------------------
__global__ void quant_blocked_kernel(const float* __restrict__ src, int n4,
                                     int K, int kshift,
                                     const float* __restrict__ sptr, float sdiv,
                                     float lo, float hi, int* __restrict__ out) {
    float s = sptr[0] / sdiv;
    int i0 = blockIdx.x * blockDim.x + threadIdx.x;
    int stride = gridDim.x * blockDim.x;
    for (int o = i0; o < n4; o += stride) {
        int blk = o >> 11;            // 2048 int-groups per 8 KB block
        int i = o & 2047;
        int v = i >> 5;               // virtual row (2 real rows)
        int sc = (i >> 2) & 7;        // stored chunk in virtual row
        int w = i & 3;                // float4 within chunk
        int vc = sc ^ (v & 7);        // unswizzled virtual chunk
        int row = (v << 1) | (vc >> 2);
        int chunk = vc & 3;
        int rowblk = blk >> kshift;
        int kblk = blk & ((1 << kshift) - 1);
        long srcoff = (long)(rowblk * 128 + row) * K + (kblk << 6) + (chunk << 4) + (w << 2);
        float4 f = *(const float4*)(src + srcoff);
        int a = (int)fminf(fmaxf(rintf(f.x / s), lo), hi);
        int b = (int)fminf(fmaxf(rintf(f.y / s), lo), hi);
        int c = (int)fminf(fmaxf(rintf(f.z / s), lo), hi);
        int d = (int)fminf(fmaxf(rintf(f.w / s), lo), hi);
        out[o] = (a & 255) | ((b & 255) << 8) | ((c & 255) << 16) | ((d & 255) << 24);
    }
}

// ---------------------------------------------------------------------------
// int8 GEMM, C[m,n] = sum_k A[m,k]*B[n,k], operands in BK=64 blocked layout
// ([rowblk][kblk][8192 B]).
// 128x128 tile, BK=64 B, 4 waves (2x2), DOUBLE-BUFFERED 2x(8+8) KiB = 32 KiB
// (same footprint as r7 -> same multi-block residency), 16 MFMA/tile.
// 2-phase counted-vmcnt loop (anti-convoy, T3/T4 minimum):
//   tile t: stage(t+1)->buf^1 (4 loads); vmcnt(4) [forces stage(t), issued a
//   FULL TILE ago -> latency self-hidden]; barrier [all waves' stage(t)
//   landed]; ds_read buf[t]; 16 MFMA under setprio; barrier [seals reads of
//   buf[t] before stage(t+2) overwrites it next iter].
// Never drains to 0 mid-loop. Race-free by the two-barrier argument above.
// ---------------------------------------------------------------------------
template <bool FIRST>
__global__ __launch_bounds__(256, 4)
void gemm_i8_kernel(const char* __restrict__ A, const char* __restrict__ B,
                    int N, int nkt,
                    const float* __restrict__ sa_ptr,
                    const float* __restrict__ wmax_ptr,
                    const float* __restrict__ bias,
                    const float* __restrict__ s2_ptr,
                    char* __restrict__ out8, float* __restrict__ outf) {
    __shared__ __align__(16) char lA[2][128 * 64];   // 2 x 8 KiB
    __shared__ __align__(16) char lB[2][128 * 64];   // 2 x 8 KiB

    const int tid = threadIdx.x;
    const int wv = tid >> 6, ln = tid & 63;
    const int lnlo = ln & 15, lnhi = ln >> 4;
    const int wr = wv >> 1, wc = wv & 1;

    int32x4 acc[4][4] = {};

    const char* pa0 = A + ((size_t)blockIdx.y * nkt << 13);
    const char* pb0 = B + ((size_t)blockIdx.x * nkt << 13);

    // stage tile t into buf[t&1]: contiguous 8 KB copy/operand, 2 loads each
    auto stage = [&](int t) {
        const int buf = t & 1;
        const char* pa = pa0 + ((size_t)t << 13);
        const char* pb = pb0 + ((size_t)t << 13);
#pragma unroll
        for (int r = 0; r < 2; ++r) {
            int off = (r * 256 + tid) * 16;
            int lbase = (r * 256 + wv * 64) * 16;  // wave-uniform base (+ln*16 HW)
            __builtin_amdgcn_global_load_lds(
                (const __attribute__((address_space(1))) void*)(pa + off),
                (__attribute__((address_space(3))) void*)(lA[buf] + lbase), 16, 0, 0);
            __builtin_amdgcn_global_load_lds(
                (const __attribute__((address_space(1))) void*)(pb + off),
                (__attribute__((address_space(3))) void*)(lB[buf] + lbase), 16, 0, 0);
        }
    };

    stage(0);

    for (int t = 0; t < nkt; ++t) {
        if (t + 1 < nkt) {
            stage(t + 1);   // issue next tile first: a full tile of flight time
            asm volatile("s_waitcnt vmcnt(4)" ::: "memory");  // stage(t) landed
        } else {
            asm volatile("s_waitcnt vmcnt(0)" ::: "memory");
        }
        __builtin_amdgcn_s_barrier();          // ALL waves' stage(t) landed
        __builtin_amdgcn_sched_barrier(0);

        const char* la = lA[t & 1];
        const char* lb = lB[t & 1];
        int32x4 af[4], bf[4];
#pragma unroll
        for (int mf = 0; mf < 4; ++mf) {
            int row = wr * 64 + mf * 16 + lnlo;
            int v = row >> 1;
            int vc = ((row & 1) << 2) | lnhi;
            af[mf] = *(const int32x4*)(la + v * 128 + ((vc ^ (v & 7)) << 4));
        }
#pragma unroll
        for (int nf = 0; nf < 4; ++nf) {
            int col = wc * 64 + nf * 16 + lnlo;
            int v = col >> 1;
            int vc = ((col & 1) << 2) | lnhi;
            bf[nf] = *(const int32x4*)(lb + v * 128 + ((vc ^ (v & 7)) << 4));
        }

        __builtin_amdgcn_s_setprio(1);
#pragma unroll
        for (int mf = 0; mf < 4; ++mf)
#pragma unroll
            for (int nf = 0; nf < 4; ++nf)
                acc[mf][nf] = __builtin_amdgcn_mfma_i32_16x16x64_i8(
                    af[mf], bf[nf], acc[mf][nf], 0, 0, 0);
        __builtin_amdgcn_s_setprio(0);
        __builtin_amdgcn_s_barrier();  // seal reads of buf[t] before overwrite
    }

    // ---- epilogue (verified r9 mapping; hq in BK=64 blocked layout) ----
    float sa = sa_ptr[0];
    float sw = wmax_ptr[0] / 7.0f;  // weight_scale
    float sab = sa * sw;
    float s2v = FIRST ? s2_ptr[0] : 0.f;

#pragma unroll
    for (int nf = 0; nf < 4; ++nf) {
        int lc = wc * 64 + nf * 16 + lnlo;               // local col 0..127
        long col = (long)blockIdx.x * 128 + lc;          // global col
        float bq = rintf(bias[col] / sab) * sab;         // Int32Bias fake-quant
#pragma unroll
        for (int mf = 0; mf < 4; ++mf) {
            int lr0 = wr * 64 + mf * 16 + (lnhi << 2);   // local row base
#pragma unroll
            for (int i = 0; i < 4; ++i) {
                int lr = lr0 + i;
                float h = sab * (float)acc[mf][nf][i] + bq;
                if constexpr (FIRST) {
                    h = fmaxf(h, 0.f);
                    float qv = fminf(fmaxf(rintf(h / s2v), 0.f), 15.f);
                    int kblk = (blockIdx.x << 1) | (lc >> 6);
                    int l6 = lc & 63;
                    int v = lr >> 1;
                    int vc = ((lr & 1) << 2) | (l6 >> 4);
                    size_t blkoff =
                        ((size_t)blockIdx.y * (gridDim.x << 1) + kblk) << 13;
                    out8[blkoff + v * 128 + ((vc ^ (v & 7)) << 4) + (lc & 15)] =
                        (char)(int)qv;
                } else {
                    outf[((long)blockIdx.y * 128 + lr) * N + col] = h;
                }
            }
        }
    }
}

// ---------------------------------------------------------------------------
// launch
// ---------------------------------------------------------------------------
extern "C" void kernel_launch(void* const* d_in, const int* in_sizes, int n_in,
                              void* d_out, int out_size, void* d_ws, size_t ws_size,
                              hipStream_t stream) {
    const float* x  = (const float*)d_in[0];   // [4,2048,2048] -> [8192,2048]
    const float* W1 = (const float*)d_in[1];   // [8192,2048]
    const float* b1 = (const float*)d_in[2];   // [8192]
    const float* W2 = (const float*)d_in[3];   // [2048,8192]
    const float* b2 = (const float*)d_in[4];   // [2048]
    const float* s1 = (const float*)d_in[5];
    const float* s2 = (const float*)d_in[6];

    const int M = 8192, D = 2048, F = 8192;

    char* ws = (char*)d_ws;
    unsigned* mx = (unsigned*)ws;          // mx[0]=maxabs(W1), mx[1]=maxabs(W2)
    char* xq  = ws + 256;                  // [M/128][D/64][8192]
    char* w1q = xq + (size_t)M * D;        // [F/128][D/64][8192]
    char* w2q = w1q + (size_t)F * D;       // [D/128][F/64][8192]
    char* hq  = w2q + (size_t)D * F;       // [M/128][F/64][8192]

    hipMemsetAsync(d_ws, 0, 8, stream);    // zero the maxabs slots

    maxabs2_kernel<<<dim3(2048, 2), 256, 0, stream>>>(W1, W2, (F * D) >> 2, mx);

    // blocked-preswizzled quant: kshift = log2(K/64)
    quant_blocked_kernel<<<2048, 256, 0, stream>>>(
        x,  (M * D) >> 2, D, 5, s1, 1.f, -8.f, 7.f, (int*)xq);
    quant_blocked_kernel<<<2048, 256, 0, stream>>>(
        W1, (F * D) >> 2, D, 5, (const float*)mx, 7.f, -8.f, 7.f, (int*)w1q);
    quant_blocked_kernel<<<2048, 256, 0, stream>>>(
        W2, (D * F) >> 2, F, 7, (const float*)(mx + 1), 7.f, -8.f, 7.f, (int*)w2q);

    // h_q = clip(round(relu(x_q W1_q^T + b1_q)/s2),0,15) -> blocked int8
    gemm_i8_kernel<true><<<dim3(F / 128, M / 128), 256, 0, stream>>>(
        xq, w1q, F, D / 64, s1, (const float*)mx, b1, s2, hq, nullptr);

    // out = s2*sw2 * (h_int W2_int^T) + b2_q
    gemm_i8_kernel<false><<<dim3(D / 128, M / 128), 256, 0, stream>>>(
        hq, w2q, D, F / 64, s2, (const float*)(mx + 1), b2, nullptr, nullptr,
        (float*)d_out);
}